// Round 1
// baseline (2505.560 us; speedup 1.0000x reference)
//
#include <hip/hip_runtime.h>
#include <math.h>

#define M_NODES 1000
#define L_EDGES 499500
#define GROUPS  500      // row pairs (g, 998-g); g==499 is self-paired (row 499)
#define NG      4        // groups per chunk/block
#define CHUNKS  125      // GROUPS / NG

__device__ __forceinline__ float wave_sum(float v){
  #pragma unroll
  for (int o = 32; o > 0; o >>= 1) v += __shfl_down(v, o);
  return v;
}

__global__ __launch_bounds__(256) void init_kernel(float* __restrict__ v0, int n){
  int i = blockIdx.x * 256 + threadIdx.x;
  if (i < n) v0[i] = 0.f;
}

// Fused edge pass: performs C_{t-1} (w_t = update, write out[t-1]) when t>=1,
// and A_t (compute p1_t, reduce DT(w_t), DT(p1_t) into partials) when t<T.
__global__ __launch_bounds__(256) void edge_pass(
    const float* __restrict__ z, float* __restrict__ out,
    const float* __restrict__ vprev, const float* __restrict__ vcur,
    const float* __restrict__ p2g,
    float* __restrict__ partA, float* __restrict__ partB,
    const float* __restrict__ gn_p, const float* __restrict__ beta_p,
    int t, int T)
{
  const int b   = blockIdx.x / CHUNKS;
  const int c   = blockIdx.x % CHUNKS;
  const int tid = threadIdx.x;
  const float gn   = gn_p[0];
  const float beta = beta_p[0];
  const float c1 = 1.f - 2.f * gn * beta;
  const float g2 = 2.f * gn;
  const bool has_c = (t >= 1);
  const bool has_a = (t < T);

  __shared__ float vp[M_NODES];  // v_{t-1}
  __shared__ float vc[M_NODES];  // v_t
  __shared__ float pp[M_NODES];  // p2_{t-1}
  __shared__ float sA[M_NODES];  // partial DT(w_t)
  __shared__ float sB[M_NODES];  // partial DT(p1_t)

  for (int i = tid; i < M_NODES; i += 256){
    sA[i] = 0.f; sB[i] = 0.f;
    if (has_c){ vp[i] = vprev[b * M_NODES + i]; pp[i] = p2g[b * M_NODES + i]; }
    if (has_a){ vc[i] = vcur[b * M_NODES + i]; }
  }
  __syncthreads();

  const float* zb    = z + (size_t)b * L_EDGES;
  const float* wprev = (t >= 2) ? out + ((size_t)b * T + (t - 2)) * L_EDGES : nullptr;
  float*       wout  = has_c    ? out + ((size_t)b * T + (t - 1)) * L_EDGES : nullptr;

  const int g0 = c * NG;
  const int g1 = (g0 + NG < GROUPS) ? (g0 + NG) : GROUPS;

  for (int g = g0; g < g1; ++g){
    #pragma unroll
    for (int half = 0; half < 2; ++half){
      const int r = half ? (998 - g) : g;
      if (half && r == g) break;          // self-paired row (g == 499)
      const int n    = 999 - r;           // edges in row r
      const int base = r * 999 - (r * (r - 1)) / 2;
      float vpr = 0.f, ppr = 0.f, vcr = 0.f;
      if (has_c){ vpr = vp[r]; ppr = pp[r]; }
      if (has_a){ vcr = vc[r]; }

      float pw = 0.f, pq = 0.f;           // row-sum partials for s[r]
      for (int k = tid; k < n; k += 256){
        const int e = base + k;
        const int j = r + 1 + k;
        const float ze = zb[e];
        float w_new;
        if (has_c){
          const float w_old = wprev ? wprev[e] : 0.f;
          const float y1 = w_old * c1 - gn * (vpr + vp[j]);
          const float p1 = fmaxf(0.f, y1 - g2 * ze);
          const float q1 = p1 * c1 - gn * (ppr + pp[j]);
          w_new = w_old - y1 + q1;
          wout[e] = w_new;
        } else {
          w_new = 0.f;                    // w_0 == 0
        }
        if (has_a){
          const float y1n = w_new * c1 - gn * (vcr + vc[j]);
          const float p1n = fmaxf(0.f, y1n - g2 * ze);
          pw += w_new;
          pq += p1n;
          atomicAdd(&sA[j], w_new);       // column contribution (distinct j per lane)
          atomicAdd(&sB[j], p1n);
        }
      }
      if (has_a){
        pw = wave_sum(pw);
        pq = wave_sum(pq);
        if ((tid & 63) == 0){
          atomicAdd(&sA[r], pw);
          atomicAdd(&sB[r], pq);
        }
      }
    }
  }

  if (has_a){
    __syncthreads();
    float* pA = partA + ((size_t)b * CHUNKS + c) * M_NODES;
    float* pB = partB + ((size_t)b * CHUNKS + c) * M_NODES;
    // chunk c only touches node indices >= g0
    for (int i = g0 + tid; i < M_NODES; i += 256){
      pA[i] = sA[i];
      pB[i] = sB[i];
    }
  }
}

// Node pass N_t: sum partials -> s_w, s_p; p2_t = prox(y2); v_{t+1} = p2 + gn*(s_p - s_w)
__global__ __launch_bounds__(256) void node_pass(
    const float* __restrict__ partA, const float* __restrict__ partB,
    const float* __restrict__ vin, float* __restrict__ vout,
    float* __restrict__ p2g,
    const float* __restrict__ gn_p, const float* __restrict__ alpha_p,
    int total)
{
  const int idx = blockIdx.x * 256 + threadIdx.x;
  if (idx >= total) return;
  const int b = idx / M_NODES;
  const int i = idx % M_NODES;
  const float gn = gn_p[0];
  const float alpha = alpha_p[0];

  const int cmax = (i / NG < CHUNKS - 1) ? (i / NG) : (CHUNKS - 1);
  float sw = 0.f, sp = 0.f;
  const float* pA = partA + (size_t)b * CHUNKS * M_NODES + i;
  const float* pB = partB + (size_t)b * CHUNKS * M_NODES + i;
  for (int cc = 0; cc <= cmax; ++cc){
    sw += pA[(size_t)cc * M_NODES];
    sp += pB[(size_t)cc * M_NODES];
  }
  const float v  = vin[idx];
  const float y2 = v + gn * sw;
  const float up = fmaxf(y2 * y2 + 4.f * gn * alpha, 1e-8f);
  const float p2v = 0.5f * (y2 - sqrtf(up));
  p2g[idx] = p2v;
  vout[idx] = p2v + gn * (sp - sw);
}

extern "C" void kernel_launch(void* const* d_in, const int* in_sizes, int n_in,
                              void* d_out, int out_size, void* d_ws, size_t ws_size,
                              hipStream_t stream)
{
  const float* z     = (const float*)d_in[0];
  const float* gn    = (const float*)d_in[1];
  const float* alpha = (const float*)d_in[2];
  const float* beta  = (const float*)d_in[3];
  const int B = in_sizes[0] / L_EDGES;      // 16
  const int T = out_size / in_sizes[0];     // 15
  float* out = (float*)d_out;

  float* ws    = (float*)d_ws;
  float* v0    = ws;                                   // B*M
  float* v1    = v0 + (size_t)B * M_NODES;             // B*M
  float* p2g   = v1 + (size_t)B * M_NODES;             // B*M
  float* partA = p2g + (size_t)B * M_NODES;            // B*CHUNKS*M
  float* partB = partA + (size_t)B * CHUNKS * M_NODES; // B*CHUNKS*M

  const int total = B * M_NODES;
  const int nodeBlocks = (total + 255) / 256;
  hipLaunchKernelGGL(init_kernel, dim3(nodeBlocks), dim3(256), 0, stream, v0, total);

  float* vbuf[2] = { v0, v1 };
  const dim3 egrid(B * CHUNKS);

  // t=0: A-only (w_0=0).  t=1..T-1: fused C_{t-1}+A_t.  t=T: C-only (final write).
  for (int t = 0; t <= T; ++t){
    const float* vprev = vbuf[((t - 1) + 2) % 2];  // v_{t-1} (unused at t=0)
    const float* vcur  = vbuf[t % 2];              // v_t     (unused at t=T)
    hipLaunchKernelGGL(edge_pass, egrid, dim3(256), 0, stream,
                       z, out, vprev, vcur, p2g, partA, partB, gn, beta, t, T);
    if (t < T){
      hipLaunchKernelGGL(node_pass, dim3(nodeBlocks), dim3(256), 0, stream,
                         partA, partB, vbuf[t % 2], vbuf[(t + 1) % 2], p2g,
                         gn, alpha, total);
    }
  }
}